// Round 1
// baseline (615.016 us; speedup 1.0000x reference)
//
#include <hip/hip_runtime.h>
#include <math.h>

#define B_ROWS 4096
#define N_ROWS 8192
#define D 128
#define INV_T 2.0f

#define RM 32
#define JN 64
#define LDS_STRIDE 129  // pad 128->129: A reads land on distinct banks, B reads 2-way (free)

// Kernel 1: L2-normalize rows of [z_i; z_j] -> Z (fp32, ws). One wave per row.
__global__ __launch_bounds__(256) void normalize_kernel(
    const float* __restrict__ z_i, const float* __restrict__ z_j,
    float* __restrict__ Z) {
  const int wave = threadIdx.x >> 6;
  const int lane = threadIdx.x & 63;
  const int row = blockIdx.x * 4 + wave;
  const float* src = (row < B_ROWS) ? (z_i + (size_t)row * D)
                                    : (z_j + (size_t)(row - B_ROWS) * D);
  float2 v = *(const float2*)(src + lane * 2);
  float ss = v.x * v.x + v.y * v.y;
#pragma unroll
  for (int off = 32; off > 0; off >>= 1) ss += __shfl_xor(ss, off);
  float norm = sqrtf(ss);
  float scale = 1.0f / fmaxf(norm, 1e-12f);
  float2 o;
  o.x = v.x * scale;
  o.y = v.y * scale;
  *(float2*)(Z + (size_t)row * D + lane * 2) = o;
}

// Kernel 2: for each row i compute  log(sum_{j!=i} exp(2*z_i.z_j)) - 2*z_i.z_partner
// Block: 32 rows x all 8192 cols, streamed in 64-col tiles through LDS.
// 256 threads = 8(ty) x 32(tx); micro-tile 4 rows x 2 cols per thread.
__global__ __launch_bounds__(256) void lse_kernel(const float* __restrict__ Z,
                                                  float* __restrict__ row_terms) {
  __shared__ float As[RM * LDS_STRIDE];
  __shared__ float Bs[JN * LDS_STRIDE];
  const int t = threadIdx.x;
  const int row0 = blockIdx.x * RM;

  // stage A tile (32 rows) once
#pragma unroll
  for (int it = 0; it < (RM * D) / 256; ++it) {
    int idx = t + it * 256;
    int r = idx >> 7, c = idx & 127;
    As[r * LDS_STRIDE + c] = Z[(size_t)(row0 + r) * D + c];
  }

  const int ty = t >> 5;  // 0..7  -> rows ty*4 .. ty*4+3
  const int tx = t & 31;  // 0..31 -> cols tx*2 .. tx*2+1
  float acc[4] = {0.f, 0.f, 0.f, 0.f};
  float pos[4] = {0.f, 0.f, 0.f, 0.f};

  for (int jt = 0; jt < N_ROWS / JN; ++jt) {
    __syncthreads();  // protects As (1st iter) and Bs reuse
#pragma unroll
    for (int it = 0; it < (JN * D) / 256; ++it) {
      int idx = t + it * 256;
      int r = idx >> 7, c = idx & 127;
      Bs[r * LDS_STRIDE + c] = Z[(size_t)(jt * JN + r) * D + c];
    }
    __syncthreads();

    float d[4][2] = {{0.f, 0.f}, {0.f, 0.f}, {0.f, 0.f}, {0.f, 0.f}};
    const float* ap = &As[(ty * 4) * LDS_STRIDE];
    const float* bp = &Bs[(tx * 2) * LDS_STRIDE];
#pragma unroll 8
    for (int k = 0; k < D; ++k) {
      float a0 = ap[k];
      float a1 = ap[LDS_STRIDE + k];
      float a2 = ap[2 * LDS_STRIDE + k];
      float a3 = ap[3 * LDS_STRIDE + k];
      float b0 = bp[k];
      float b1 = bp[LDS_STRIDE + k];
      d[0][0] += a0 * b0; d[0][1] += a0 * b1;
      d[1][0] += a1 * b0; d[1][1] += a1 * b1;
      d[2][0] += a2 * b0; d[2][1] += a2 * b1;
      d[3][0] += a3 * b0; d[3][1] += a3 * b1;
    }

#pragma unroll
    for (int r = 0; r < 4; ++r) {
      int gi = row0 + ty * 4 + r;
      int partner = (gi < B_ROWS) ? gi + B_ROWS : gi - B_ROWS;
#pragma unroll
      for (int c = 0; c < 2; ++c) {
        int gj = jt * JN + tx * 2 + c;
        float s = d[r][c] * INV_T;  // logits bounded in [-2,2]: exp is safe
        float e = __expf(s);
        if (gj != gi) acc[r] += e;      // diag excluded
        if (gj == partner) pos[r] = s;  // exactly one j matches per row
      }
    }
  }

  // reduce acc/pos across the 32 tx lanes sharing the same rows
#pragma unroll
  for (int r = 0; r < 4; ++r) {
    float a = acc[r], p = pos[r];
#pragma unroll
    for (int off = 16; off > 0; off >>= 1) {
      a += __shfl_xor(a, off);
      p += __shfl_xor(p, off);
    }
    if (tx == 0) {
      int gi = row0 + ty * 4 + r;
      row_terms[gi] = logf(a) - p;
    }
  }
}

// Kernel 3: deterministic sum of 8192 row terms -> loss scalar
__global__ __launch_bounds__(256) void reduce_kernel(const float* __restrict__ rt,
                                                     float* __restrict__ out) {
  __shared__ float wsum[4];
  float s = 0.f;
  for (int i = threadIdx.x; i < N_ROWS; i += 256) s += rt[i];
#pragma unroll
  for (int off = 32; off > 0; off >>= 1) s += __shfl_xor(s, off);
  const int wave = threadIdx.x >> 6;
  const int lane = threadIdx.x & 63;
  if (lane == 0) wsum[wave] = s;
  __syncthreads();
  if (threadIdx.x == 0)
    out[0] = (wsum[0] + wsum[1] + wsum[2] + wsum[3]) / (float)N_ROWS;
}

extern "C" void kernel_launch(void* const* d_in, const int* in_sizes, int n_in,
                              void* d_out, int out_size, void* d_ws, size_t ws_size,
                              hipStream_t stream) {
  const float* z_i = (const float*)d_in[0];
  const float* z_j = (const float*)d_in[1];
  float* out = (float*)d_out;
  float* Z = (float*)d_ws;                 // 8192*128 fp32 = 4 MB
  float* rt = Z + (size_t)N_ROWS * D;      // 8192 fp32

  hipLaunchKernelGGL(normalize_kernel, dim3(N_ROWS / 4), dim3(256), 0, stream,
                     z_i, z_j, Z);
  hipLaunchKernelGGL(lse_kernel, dim3(N_ROWS / RM), dim3(256), 0, stream, Z, rt);
  hipLaunchKernelGGL(reduce_kernel, dim3(1), dim3(256), 0, stream, rt, out);
}

// Round 2
// 103.936 us; speedup vs baseline: 5.9173x; 5.9173x over previous
//
#include <hip/hip_runtime.h>
#include <hip/hip_bf16.h>
#include <math.h>

#define B_ROWS 4096
#define N_ROWS 8192
#define D 128
#define INV_T 2.0f
#define CHUNKS 8          // column chunks per row-tile
#define JT_PER_CHUNK 8    // 8 j-tiles x 128 cols = 1024 cols per chunk

typedef __attribute__((ext_vector_type(8))) short bf16x8;
typedef __attribute__((ext_vector_type(4))) float f32x4;

// ---------------- Kernel 1: L2-normalize rows -> bf16 Z ----------------
__global__ __launch_bounds__(256) void normalize_kernel(
    const float* __restrict__ z_i, const float* __restrict__ z_j,
    ushort* __restrict__ Z) {
  const int wave = threadIdx.x >> 6;
  const int lane = threadIdx.x & 63;
  const int row = blockIdx.x * 4 + wave;
  const float* src = (row < B_ROWS) ? (z_i + (size_t)row * D)
                                    : (z_j + (size_t)(row - B_ROWS) * D);
  float2 v = *(const float2*)(src + lane * 2);
  float ss = v.x * v.x + v.y * v.y;
#pragma unroll
  for (int off = 32; off > 0; off >>= 1) ss += __shfl_xor(ss, off);
  float scale = 1.0f / fmaxf(sqrtf(ss), 1e-12f);
  __hip_bfloat16 h0 = __float2bfloat16(v.x * scale);
  __hip_bfloat16 h1 = __float2bfloat16(v.y * scale);
  ushort2 o;
  o.x = *(ushort*)&h0;
  o.y = *(ushort*)&h1;
  *(ushort2*)(Z + (size_t)row * D + lane * 2) = o;
}

// ---------------- Kernel 2: MFMA exp-rowsum ----------------
// Block: 256 threads = 4 waves in 2x2 (wy,wx). Row tile 128, col slab 1024.
// A fragments (wave's 64 rows x K=128) stay in registers for the whole slab.
// 16x16x32 bf16 MFMA. A/B frag: lane holds [m|n = lane&15][k = (lane>>4)*8 + j]
// = 16 contiguous bytes of Z. C frag: col = lane&15, row = (lane>>4)*4 + reg.
__global__ __launch_bounds__(256) void sim_kernel(
    const ushort* __restrict__ Z, float* __restrict__ partials,
    float* __restrict__ pos_buf) {
  const int t = threadIdx.x;
  const int lane = t & 63;
  const int w = t >> 6;
  const int wy = w >> 1, wx = w & 1;
  const int l15 = lane & 15;
  const int l4 = lane >> 4;  // 0..3
  const int row0 = blockIdx.x * 128;
  const int chunk = blockIdx.y;

  // Load A fragments: 4 row-subtiles x 4 K-subtiles, 16B/lane each.
  bf16x8 a[4][4];
  const int arow = row0 + wy * 64 + l15;
#pragma unroll
  for (int rs = 0; rs < 4; ++rs)
#pragma unroll
    for (int ks = 0; ks < 4; ++ks)
      a[rs][ks] = *(const bf16x8*)(Z + (size_t)(arow + rs * 16) * D + ks * 32 + l4 * 8);

  float rowsum[4][4];
#pragma unroll
  for (int rs = 0; rs < 4; ++rs)
#pragma unroll
    for (int r = 0; r < 4; ++r) rowsum[rs][r] = 0.f;

  for (int jt = 0; jt < JT_PER_CHUNK; ++jt) {
    const int colb = chunk * 1024 + jt * 128 + wx * 64;
#pragma unroll
    for (int cs = 0; cs < 4; ++cs) {
      // B fragments for this 16-col subtile (4 K-subtiles)
      bf16x8 b[4];
      const int bcol = colb + cs * 16 + l15;
#pragma unroll
      for (int ks = 0; ks < 4; ++ks)
        b[ks] = *(const bf16x8*)(Z + (size_t)bcol * D + ks * 32 + l4 * 8);

      f32x4 c[4];
#pragma unroll
      for (int rs = 0; rs < 4; ++rs) c[rs] = (f32x4){0.f, 0.f, 0.f, 0.f};
#pragma unroll
      for (int ks = 0; ks < 4; ++ks)
#pragma unroll
        for (int rs = 0; rs < 4; ++rs)
          c[rs] = __builtin_amdgcn_mfma_f32_16x16x32_bf16(a[rs][ks], b[ks], c[rs], 0, 0, 0);

      const int gj = colb + cs * 16 + l15;
#pragma unroll
      for (int rs = 0; rs < 4; ++rs) {
        const int gibase = row0 + wy * 64 + rs * 16 + l4 * 4;
#pragma unroll
        for (int reg = 0; reg < 4; ++reg) {
          const int gi = gibase + reg;
          float s = c[rs][reg] * INV_T;  // logits bounded ~[-2,2]
          float e = __expf(s);
          rowsum[rs][reg] += (gi != gj) ? e : 0.f;     // mask diag exactly
          if ((gi ^ gj) == B_ROWS) pos_buf[gi] = s;    // exactly once per row
        }
      }
    }
  }

  // Reduce rowsum across the 16 column-lanes (low 4 lane bits)
#pragma unroll
  for (int rs = 0; rs < 4; ++rs)
#pragma unroll
    for (int r = 0; r < 4; ++r) {
      float v = rowsum[rs][r];
      v += __shfl_xor(v, 1);
      v += __shfl_xor(v, 2);
      v += __shfl_xor(v, 4);
      v += __shfl_xor(v, 8);
      rowsum[rs][r] = v;
    }

  // Combine the two wx-waves via LDS, then one write per (row, chunk).
  __shared__ float rs_lds[128];
  if (wx == 0 && l15 == 0) {
#pragma unroll
    for (int rs = 0; rs < 4; ++rs)
#pragma unroll
      for (int r = 0; r < 4; ++r)
        rs_lds[wy * 64 + rs * 16 + l4 * 4 + r] = rowsum[rs][r];
  }
  __syncthreads();
  if (wx == 1 && l15 == 0) {
#pragma unroll
    for (int rs = 0; rs < 4; ++rs)
#pragma unroll
      for (int r = 0; r < 4; ++r)
        rs_lds[wy * 64 + rs * 16 + l4 * 4 + r] += rowsum[rs][r];
  }
  __syncthreads();
  if (t < 128)
    partials[(size_t)(row0 + t) * CHUNKS + chunk] = rs_lds[t];
}

// ---------------- Kernel 3: per-row term + block partial sums ----------------
__global__ __launch_bounds__(128) void reduce1_kernel(
    const float* __restrict__ partials, const float* __restrict__ pos_buf,
    float* __restrict__ loss_part) {
  const int row = blockIdx.x * 128 + threadIdx.x;
  float tot = 0.f;
#pragma unroll
  for (int c = 0; c < CHUNKS; ++c) tot += partials[(size_t)row * CHUNKS + c];
  float term = logf(tot) - pos_buf[row];
  // reduce 128 threads = 2 waves
#pragma unroll
  for (int off = 32; off > 0; off >>= 1) term += __shfl_xor(term, off);
  __shared__ float wsum[2];
  if ((threadIdx.x & 63) == 0) wsum[threadIdx.x >> 6] = term;
  __syncthreads();
  if (threadIdx.x == 0) loss_part[blockIdx.x] = wsum[0] + wsum[1];
}

// ---------------- Kernel 4: final 64 -> 1 ----------------
__global__ __launch_bounds__(64) void reduce2_kernel(
    const float* __restrict__ loss_part, float* __restrict__ out) {
  float v = loss_part[threadIdx.x];
#pragma unroll
  for (int off = 32; off > 0; off >>= 1) v += __shfl_xor(v, off);
  if (threadIdx.x == 0) out[0] = v / (float)N_ROWS;
}

extern "C" void kernel_launch(void* const* d_in, const int* in_sizes, int n_in,
                              void* d_out, int out_size, void* d_ws, size_t ws_size,
                              hipStream_t stream) {
  const float* z_i = (const float*)d_in[0];
  const float* z_j = (const float*)d_in[1];
  float* out = (float*)d_out;

  ushort* Z = (ushort*)d_ws;                                   // 2 MB
  float* partials = (float*)((char*)d_ws + (size_t)N_ROWS * D * sizeof(ushort));
  float* pos_buf = partials + (size_t)N_ROWS * CHUNKS;         // 256 KB after 2 MB
  float* loss_part = pos_buf + N_ROWS;                         // 32 KB after

  hipLaunchKernelGGL(normalize_kernel, dim3(N_ROWS / 4), dim3(256), 0, stream,
                     z_i, z_j, Z);
  hipLaunchKernelGGL(sim_kernel, dim3(N_ROWS / 128, CHUNKS), dim3(256), 0,
                     stream, Z, partials, pos_buf);
  hipLaunchKernelGGL(reduce1_kernel, dim3(N_ROWS / 128), dim3(128), 0, stream,
                     partials, pos_buf, loss_part);
  hipLaunchKernelGGL(reduce2_kernel, dim3(1), dim3(64), 0, stream, loss_part,
                     out);
}